// Round 1
// baseline (99.624 us; speedup 1.0000x reference)
//
#include <hip/hip_runtime.h>

// ChamferLoss: x,y (16,4096,3) f32 -> scalar.
// R9: occupancy fix. rocprof showed VALUBusy=98% but dur = 2.03x the VALU
// issue floor (23.9us). VALUBusy is computed with the gfx942 SIMD-16 formula
// (4 cyc/instr); gfx950 is SIMD-32 (2 cyc) -> true issue occupancy ~49%.
// The kernel was latency-bound at 2 waves/SIMD (2 blocks/CU x 4 waves,
// OccupancyPercent=17). Fix: BLK 256->512 (8 waves/block), RQ 8->4, grid
// unchanged (512 blocks = 2/CU, full-DB 64KB LDS kept) -> 16 waves/CU =
// 4 waves/SIMD. Also force v_min3_f32 via inline asm (fminf(fminf(..)) may
// not fuse without fast-math).
// VALU floor: 536.9M pairs x 3.5 ops = 23.9us; target ~28-34us.

#define NP 4096
#define NB 16
#define BLK 512
#define NZZ (2 * NB)            // 32 (dir,b)
#define RQ 4                    // queries per lane
#define QPB 256                 // queries per block (8 waves * 8 tq * RQ)
#define BPZ (NP / QPB)          // 16 blocks per zz
#define NBLOCKS (NZZ * BPZ)     // 512

__global__ void chamfer_init(float* __restrict__ out) { out[0] = 0.0f; }

__device__ __forceinline__ float fmin3(float a, float b, float c) {
  float d;
  asm("v_min3_f32 %0, %1, %2, %3" : "=v"(d) : "v"(a), "v"(b), "v"(c));
  return d;
}

__global__ __launch_bounds__(BLK, 4) void chamfer_main(
    const float* __restrict__ x, const float* __restrict__ y,
    float* __restrict__ out) {
  const int bid  = blockIdx.x;
  const int zz   = bid >> 4;          // /BPZ
  const int qblk = bid & (BPZ - 1);
  const int dir  = zz >> 4;
  const int b    = zz & 15;

  const float* q_base = (dir == 0 ? x : y) + (size_t)b * NP * 3;
  const float* d_base = (dir == 0 ? y : x) + (size_t)b * NP * 3;

  // ---- stage full db (4096 pts) into LDS as (x,y,z,d2) ----
  __shared__ float4 dpt[NP];          // 64 KB
  for (int p = threadIdx.x; p < NP; p += BLK) {
    const float dx = d_base[p * 3 + 0];
    const float dy = d_base[p * 3 + 1];
    const float dz = d_base[p * 3 + 2];
    dpt[p] = make_float4(dx, dy, dz, dx * dx + dy * dy + dz * dz);
  }
  __syncthreads();

  const int wid  = threadIdx.x >> 6;  // wave 0..7
  const int lane = threadIdx.x & 63;
  const int td   = lane & 7;          // db slice 0..7
  const int tq   = lane >> 3;         // query group 0..7

  // this lane's RQ queries
  float qpx[RQ], qpy[RQ], qpz[RQ], q2[RQ], m[RQ];
#pragma unroll
  for (int r = 0; r < RQ; ++r) {
    const int qi = qblk * QPB + wid * (8 * RQ) + tq * RQ + r;
    const float qx = q_base[qi * 3 + 0];
    const float qy = q_base[qi * 3 + 1];
    const float qz = q_base[qi * 3 + 2];
    q2[r]  = qx * qx + qy * qy + qz * qz;
    qpx[r] = -2.0f * qx;
    qpy[r] = -2.0f * qy;
    qpz[r] = -2.0f * qz;
    m[r]   = 3.4e38f;
  }

  // ---- min over this lane's db slice: points t*8+td, t in [0,512) ----
#pragma unroll 4
  for (int t = 0; t < NP / 8; t += 2) {
    const float4 d0 = dpt[t * 8 + td];
    const float4 d1 = dpt[(t + 1) * 8 + td];
#pragma unroll
    for (int r = 0; r < RQ; ++r) {
      const float v0 = fmaf(d0.x, qpx[r], fmaf(d0.y, qpy[r], fmaf(d0.z, qpz[r], d0.w)));
      const float v1 = fmaf(d1.x, qpx[r], fmaf(d1.y, qpy[r], fmaf(d1.z, qpz[r], d1.w)));
      m[r] = fmin3(v0, v1, m[r]);
    }
  }

  // ---- reduce mins across the 8 td lanes of each octet ----
#pragma unroll
  for (int r = 0; r < RQ; ++r) {
    m[r] = fminf(m[r], __shfl_xor(m[r], 1));
    m[r] = fminf(m[r], __shfl_xor(m[r], 2));
    m[r] = fminf(m[r], __shfl_xor(m[r], 4));
  }

  // ---- epilogue: sqrt + partial mean (td==0 lanes only) ----
  float local = 0.0f;
  if (td == 0) {
#pragma unroll
    for (int r = 0; r < RQ; ++r)
      local += sqrtf(fmaxf(q2[r] + m[r], 0.0f) + 1e-6f);
    local *= (1.0f / (float)(NB * NP));
  }

  // wave reduce (octet leaders), then block reduce, one atomic per block
#pragma unroll
  for (int off = 32; off > 0; off >>= 1)
    local += __shfl_down(local, off);

  __shared__ float wsum[BLK / 64];
  if (lane == 0) wsum[wid] = local;
  __syncthreads();
  if (threadIdx.x == 0) {
    float s = 0.0f;
#pragma unroll
    for (int w = 0; w < BLK / 64; ++w) s += wsum[w];
    atomicAdd(out, s);
  }
}

extern "C" void kernel_launch(void* const* d_in, const int* in_sizes, int n_in,
                              void* d_out, int out_size, void* d_ws, size_t ws_size,
                              hipStream_t stream) {
  const float* x = (const float*)d_in[0];
  const float* y = (const float*)d_in[1];
  float* out = (float*)d_out;

  chamfer_init<<<1, 64, 0, stream>>>(out);
  chamfer_main<<<NBLOCKS, BLK, 0, stream>>>(x, y, out);
}